// Round 1
// 540.661 us; speedup vs baseline: 1.0052x; 1.0052x over previous
//
#include <hip/hip_runtime.h>
#include <hip/hip_bf16.h>
#include <math.h>

// Problem constants
#define B_    16
#define CE_   128
#define CB_   256
#define H_    56
#define W_    56
#define NH_   8
#define WS_   7
#define HD_   32
#define NWIN_ 49      // WS*WS
#define HW_   3136    // H*W
#define M_    50176   // B*H*W rows
#define HID_  1024

typedef short bf16x8 __attribute__((ext_vector_type(8)));
typedef float f32x4  __attribute__((ext_vector_type(4)));

__device__ __forceinline__ float waveRedSum(float v) {
#pragma unroll
  for (int off = 32; off; off >>= 1) v += __shfl_xor(v, off, 64);
  return v;
}

// Async global->LDS, 16B per lane.  LDS dest = wave-uniform base + lane*16.
__device__ __forceinline__ void load_lds16(const void* g, void* l) {
  __builtin_amdgcn_global_load_lds((__attribute__((address_space(1))) void*)g,
                                   (__attribute__((address_space(3))) void*)l,
                                   16, 0, 0);
}

// ---------------------------------------------------------------------------
// x_edge stats, stage 1: 1024 blocks (64 per batch), partial sums to ws.
__global__ void k_stats1(const float* __restrict__ xe, float* __restrict__ part) {
  int blk = blockIdx.x;
  int b = blk >> 6, s = blk & 63;
  const float4* p = (const float4*)(xe + (size_t)b * 401408 + s * 6272);
  float sm = 0.f, s2 = 0.f;
  for (int i = threadIdx.x; i < 1568; i += 256) {
    float4 v = p[i];
    sm += v.x + v.y + v.z + v.w;
    s2 += v.x * v.x + v.y * v.y + v.z * v.z + v.w * v.w;
  }
  sm = waveRedSum(sm); s2 = waveRedSum(s2);
  __shared__ float aux[8];
  int wave = threadIdx.x >> 6, lane = threadIdx.x & 63;
  if (lane == 0) { aux[wave] = sm; aux[4 + wave] = s2; }
  __syncthreads();
  if (threadIdx.x == 0) {
    part[blk * 2]     = aux[0] + aux[1] + aux[2] + aux[3];
    part[blk * 2 + 1] = aux[4] + aux[5] + aux[6] + aux[7];
  }
}

// stage 2: 16 blocks x 64 threads -> mean/rstd per batch.
__global__ void k_stats2(const float* __restrict__ part, float* __restrict__ stats) {
  int b = blockIdx.x, lane = threadIdx.x;
  float sm = part[(b * 64 + lane) * 2];
  float s2 = part[(b * 64 + lane) * 2 + 1];
  sm = waveRedSum(sm); s2 = waveRedSum(s2);
  if (lane == 0) {
    float mean = sm / 401408.0f;
    float var  = s2 / 401408.0f - mean * mean;
    stats[b * 2] = mean;
    stats[b * 2 + 1] = rsqrtf(var + 1e-5f);
  }
}

// ---------------------------------------------------------------------------
// Cast weight matrices fp32 -> bf16 into one contiguous buffer.
__global__ void k_cast6(const float* __restrict__ s0, const float* __restrict__ s1,
                        const float* __restrict__ s2, const float* __restrict__ s3,
                        const float* __restrict__ s4, const float* __restrict__ s5,
                        __hip_bfloat16* __restrict__ d) {
  size_t i4 = ((size_t)blockIdx.x * 256 + threadIdx.x) * 4;
  if (i4 >= 819200) return;
  const float* src; size_t off;
  if      (i4 < 32768)  { src = s0; off = 0; }
  else if (i4 < 98304)  { src = s1; off = 32768; }
  else if (i4 < 229376) { src = s2; off = 98304; }
  else if (i4 < 294912) { src = s3; off = 229376; }
  else if (i4 < 557056) { src = s4; off = 294912; }
  else                  { src = s5; off = 557056; }
  float4 v = *(const float4*)(src + (i4 - off));
  union { __hip_bfloat16 h[4]; uint2 u; } pk;
  pk.h[0] = __float2bfloat16(v.x);
  pk.h[1] = __float2bfloat16(v.y);
  pk.h[2] = __float2bfloat16(v.z);
  pk.h[3] = __float2bfloat16(v.w);
  *(uint2*)(d + i4) = pk.u;
}

// ---------------------------------------------------------------------------
// W_qc = qscale * q_w(256x256) @ conv_w(256x128) -> bf16 (256x128 row-major).
// Folds the 1x1 conv into the Q projection (xec eliminated).
// 256 blocks x 128 threads; q_w row access is block-uniform (scalarized).
__global__ void k_wqc(const float* __restrict__ qw, const float* __restrict__ cw,
                      __hip_bfloat16* __restrict__ wqc) {
  int o2 = blockIdx.x, c = threadIdx.x;
  float acc = 0.f;
#pragma unroll 4
  for (int o = 0; o < 256; ++o)
    acc += qw[o2 * 256 + o] * cw[o * 128 + c];
  wqc[o2 * 128 + c] = __float2bfloat16(acc * 0.17677669529663687f);
}

// ---------------------------------------------------------------------------
// Precompute rel-pos bias in MFMA C-fragment order + padding mask.
__global__ void k_bias_pre(const float* __restrict__ rpb, float* __restrict__ bp) {
  int blk = blockIdx.x;         // h*16 + ti*4 + tj
  int h = blk >> 4, tile = blk & 15;
  int ti = tile >> 2, tj = tile & 3;
  int lane = threadIdx.x;
  int quad = lane >> 4, lm = lane & 15;
  float4 v;
  float* vp = (float*)&v;
#pragma unroll
  for (int r = 0; r < 4; ++r) {
    int i = ti * 16 + quad * 4 + r;
    int j = tj * 16 + lm;
    float b = -1e30f;
    if (i < 49 && j < 49) {
      int rel = (i / 7 - j / 7 + 6) * 13 + (i % 7 - j % 7 + 6);
      b = rpb[rel * 8 + h];
    }
    vp[r] = b;
  }
  *(float4*)&bp[(size_t)(blk * 64 + lane) * 4] = v;
}

// ---------------------------------------------------------------------------
// Normalize x_edge (per-element affine), emit bf16 A matrix in WINDOWED row
// order: row m = wb*49 + p, cols = 128 channels.  1024 blocks (one/window).
__global__ void k_prep_edge(const float* __restrict__ xe,
                            const float* __restrict__ we,
                            const float* __restrict__ be,
                            const float* __restrict__ stats,
                            __hip_bfloat16* __restrict__ Ae) {
  int wb = blockIdx.x;
  int b = wb >> 6, rem = wb & 63;
  int h0 = (rem >> 3) * 7, w0 = (rem & 7) * 7;
  float mean = stats[b * 2], rstd = stats[b * 2 + 1];
  __shared__ __hip_bfloat16 t[49 * 130];
  for (int idx = threadIdx.x; idx < 128 * 49; idx += 256) {
    int c = idx / 49, p = idx % 49;
    int h = h0 + p / 7, w = w0 + p % 7;
    int off = (c * 56 + h) * 56 + w;
    float v = xe[(size_t)b * 401408 + off];
    t[p * 130 + c] = __float2bfloat16((v - mean) * rstd * we[off] + be[off]);
  }
  __syncthreads();
  __hip_bfloat16* dst = Ae + (size_t)wb * 49 * 128;
  for (int idx = threadIdx.x; idx < 49 * 128; idx += 256) {
    int p = idx >> 7, c = idx & 127;
    dst[idx] = t[p * 130 + c];
  }
}

// ---------------------------------------------------------------------------
// Row LayerNorm over 256 channels; one wave per row, 4 rows/block.
template <bool PERM>
__global__ void k_ln_rows(const float* __restrict__ x,
                          const float* __restrict__ w,
                          const float* __restrict__ bia,
                          __hip_bfloat16* __restrict__ out) {
  int row = blockIdx.x * 4 + (threadIdx.x >> 6);
  int lane = threadIdx.x & 63;
  float4 xv = *(const float4*)(x + (size_t)row * 256 + lane * 4);
  float s  = xv.x + xv.y + xv.z + xv.w;
  float s2 = xv.x * xv.x + xv.y * xv.y + xv.z * xv.z + xv.w * xv.w;
  s = waveRedSum(s); s2 = waveRedSum(s2);
  float mean = s * (1.0f / 256.0f);
  float var  = s2 * (1.0f / 256.0f) - mean * mean;
  float rstd = rsqrtf(var + 1e-5f);
  int orow = row;
  if (PERM) {
    int b = row / 3136, hw = row % 3136;
    int h = hw / 56, ww = hw % 56;
    orow = (b * 64 + (h / 7) * 8 + (ww / 7)) * 49 + (h % 7) * 7 + (ww % 7);
  }
  float4 wv = *(const float4*)(w + lane * 4);
  float4 bv = *(const float4*)(bia + lane * 4);
  union { __hip_bfloat16 h[4]; uint2 u; } pk;
  pk.h[0] = __float2bfloat16((xv.x - mean) * rstd * wv.x + bv.x);
  pk.h[1] = __float2bfloat16((xv.y - mean) * rstd * wv.y + bv.y);
  pk.h[2] = __float2bfloat16((xv.z - mean) * rstd * wv.z + bv.z);
  pk.h[3] = __float2bfloat16((xv.w - mean) * rstd * wv.w + bv.w);
  *(uint2*)(out + (size_t)orow * 256 + lane * 4) = pk.u;
}

// ---------------------------------------------------------------------------
// MFMA GEMM:  C(MxN) = A(MxK,bf16) * W(NxK,bf16)^T   with epilogues.
// 128x128 tile, BK=32, 256 threads.  1-D grid of 392*NX blocks with
// XCD-aware swizzle: xcd=lin&7 owns m-bands [xcd*49, xcd*49+49), sweeping
// the NX n-tiles of a band consecutively (A-tile stays in that XCD's L2).
//
// K-loop: T3 minimum 2-phase double-buffered schedule — issue next tile's
// global_load_lds BEFORE current tile's ds_read+MFMA; single
// s_waitcnt vmcnt(0) + raw s_barrier per K-tile (no full __syncthreads
// drain; loads stay in flight under the MFMA cluster).
//
// EPI: 0 store bf16 | 2 proj(+bias+resid, permute rows, f32)
//      3 bias+gelu(tanh) bf16 | 4 bias+resid f32
template <int EPI, int NX>
__launch_bounds__(256)
__global__ void gemm_bt(const __hip_bfloat16* __restrict__ A,
                        const __hip_bfloat16* __restrict__ Bw,
                        int M, int N, int K,
                        __hip_bfloat16* __restrict__ outb,
                        float* __restrict__ outf,
                        const float* __restrict__ bias,
                        const float* __restrict__ resid) {
  __shared__ __hip_bfloat16 As[2][128 * 32];  // 2 x 8 KB
  __shared__ __hip_bfloat16 Bs[2][128 * 32];  // 2 x 8 KB
  const int tid  = threadIdx.x;
  const int lane = tid & 63;
  const int wave = tid >> 6;
  const int quad = lane >> 4;
  const int lm   = lane & 15;
  const int wm   = (wave & 1) << 6;
  const int wn   = (wave >> 1) << 6;
  // XCD-aware swizzle (392 bands = 8 XCDs x 49)
  const int lin  = blockIdx.x;
  const int slot = lin >> 3;
  const int band = (lin & 7) * 49 + slot / NX;
  const int n0   = (slot % NX) * 128;
  const int m0   = band * 128;

  const int rh = (wave & 1) * 64;   // row-half base
  const int qw = wave >> 1;         // base k-quad
  const __hip_bfloat16* Arow = A  + (size_t)(m0 + rh + lane) * K;
  const __hip_bfloat16* Brow = Bw + (size_t)(n0 + rh + lane) * K;

  f32x4 acc[4][4];
#pragma unroll
  for (int i = 0; i < 4; ++i)
#pragma unroll
    for (int j = 0; j < 4; ++j)
#pragma unroll
      for (int r = 0; r < 4; ++r) acc[i][j][r] = 0.f;

  // stage one BK=32 tile (A+B) into buffer `buf`
  auto STAGE = [&](int buf, int k0) {
#pragma unroll
    for (int p = 0; p < 2; ++p) {
      int q = qw + 2 * p;
      load_lds16(Arow + k0 + q * 8, &As[buf][(q * 128 + rh) * 8]);
      load_lds16(Brow + k0 + q * 8, &Bs[buf][(q * 128 + rh) * 8]);
    }
  };

  const int nt = K >> 5;
  // prologue: fill buffer 0, drain, barrier
  STAGE(0, 0);
  asm volatile("s_waitcnt vmcnt(0)" ::: "memory");
  __builtin_amdgcn_s_barrier();
  __builtin_amdgcn_sched_barrier(0);

  int cur = 0;
  for (int t = 0; t < nt; ++t) {
    // issue next tile's loads first — they fly under this tile's MFMAs
    if (t + 1 < nt) STAGE(cur ^ 1, (t + 1) << 5);
    bf16x8 af[4], bfr[4];
#pragma unroll
    for (int i = 0; i < 4; ++i)
      af[i] = *(const bf16x8*)&As[cur][(quad * 128 + wm + i * 16 + lm) * 8];
#pragma unroll
    for (int j = 0; j < 4; ++j)
      bfr[j] = *(const bf16x8*)&Bs[cur][(quad * 128 + wn + j * 16 + lm) * 8];
#pragma unroll
    for (int i = 0; i < 4; ++i)
#pragma unroll
      for (int j = 0; j < 4; ++j)
        acc[i][j] = __builtin_amdgcn_mfma_f32_16x16x32_bf16(af[i], bfr[j], acc[i][j], 0, 0, 0);
    if (t + 1 < nt) {
      // wait only once per tile; prefetch latency already covered by MFMAs
      asm volatile("s_waitcnt vmcnt(0)" ::: "memory");
      __builtin_amdgcn_s_barrier();
      __builtin_amdgcn_sched_barrier(0);
    }
    cur ^= 1;
  }

  // epilogue: loops ordered i->r->j so row-derived values (gm, nat) hoist
#pragma unroll
  for (int i = 0; i < 4; ++i) {
#pragma unroll
    for (int r = 0; r < 4; ++r) {
      int gm = m0 + wm + i * 16 + quad * 4 + r;
      size_t rowbase;
      if constexpr (EPI == 2) {
        int wb = gm / 49, nn = gm % 49;
        int b = wb >> 6, rem = wb & 63;
        int h = (rem >> 3) * 7 + nn / 7, w = (rem & 7) * 7 + nn % 7;
        rowbase = (size_t)(b * 3136 + h * 56 + w) * 256;
      } else {
        rowbase = (size_t)gm * N;
      }
#pragma unroll
      for (int j = 0; j < 4; ++j) {
        int gn = n0 + wn + j * 16 + lm;
        float v = acc[i][j][r];
        if constexpr (EPI == 0) {
          outb[rowbase + gn] = __float2bfloat16(v);
        } else if constexpr (EPI == 2) {
          outf[rowbase + gn] = v + bias[gn] + resid[rowbase + gn];
        } else if constexpr (EPI == 3) {
          float x = v + bias[gn];
          float y = 0.7978845608028654f * (x + 0.044715f * x * x * x);
          float e = __expf(2.0f * y);
          float th = 1.0f - 2.0f / (e + 1.0f);
          outb[rowbase + gn] = __float2bfloat16(0.5f * x * (1.0f + th));
        } else {  // EPI == 4
          outf[rowbase + gn] = v + bias[gn] + resid[rowbase + gn];
        }
      }
    }
  }
}

// ---------------------------------------------------------------------------
// MFMA windowed attention: one WAVE per (window, head).  8192 blocks x 64 thr.
__launch_bounds__(64)
__global__ void k_attn_mfma(const __hip_bfloat16* __restrict__ qb,
                            const __hip_bfloat16* __restrict__ kvb,
                            const float* __restrict__ bp,
                            __hip_bfloat16* __restrict__ ob) {
  int wb = blockIdx.x >> 3;
  int h  = blockIdx.x & 7;
  __shared__ __align__(16) __hip_bfloat16 lds[7424];
  __hip_bfloat16* Qs = lds;
  __hip_bfloat16* Ks = lds + 2560;
  __hip_bfloat16* Vt = lds + 5120;
  __hip_bfloat16* Ps = lds;
  const int lane = threadIdx.x;
  const int quad = lane >> 4, lm = lane & 15;

  const __hip_bfloat16 zb = __float2bfloat16(0.f);
  for (int i = lane; i < 600; i += 64) { Qs[1960 + i] = zb; Ks[1960 + i] = zb; }
  {
    uint4 z; z.x = z.y = z.z = z.w = 0u;
    for (int i = lane; i < 288; i += 64) ((uint4*)Vt)[i] = z;
  }
  {
    int t = lane >> 2, p = lane & 3;
#pragma unroll
    for (int pass = 0; pass < 4; ++pass, t += 16) {
      if (t < 49) {
        size_t rq = (size_t)(wb * 49 + t);
        uint4 qv = *(const uint4*)(qb + rq * 256 + h * 32 + p * 8);
        *(uint4*)&Qs[t * 40 + p * 8] = qv;
        uint4 kv = *(const uint4*)(kvb + rq * 512 + h * 32 + p * 8);
        *(uint4*)&Ks[t * 40 + p * 8] = kv;
        union { uint4 u; __hip_bfloat16 e[8]; } vv;
        vv.u = *(const uint4*)(kvb + rq * 512 + 256 + h * 32 + p * 8);
#pragma unroll
        for (int i = 0; i < 8; ++i) Vt[(p * 8 + i) * 72 + t] = vv.e[i];
      }
    }
  }
  __builtin_amdgcn_s_waitcnt(0);

  bf16x8 qf[4], kf[4];
#pragma unroll
  for (int i = 0; i < 4; ++i) qf[i] = *(const bf16x8*)&Qs[(i * 16 + lm) * 40 + quad * 8];
#pragma unroll
  for (int j = 0; j < 4; ++j) kf[j] = *(const bf16x8*)&Ks[(j * 16 + lm) * 40 + quad * 8];
  f32x4 s[4][4];
#pragma unroll
  for (int i = 0; i < 4; ++i)
#pragma unroll
    for (int j = 0; j < 4; ++j) {
      f32x4 z4; z4[0] = z4[1] = z4[2] = z4[3] = 0.f;
      s[i][j] = __builtin_amdgcn_mfma_f32_16x16x32_bf16(qf[i], kf[j], z4, 0, 0, 0);
    }
#pragma unroll
  for (int ti = 0; ti < 4; ++ti)
#pragma unroll
    for (int tj = 0; tj < 4; ++tj) {
      f32x4 b = *(const f32x4*)&bp[(size_t)(((h * 4 + ti) * 4 + tj) * 64 + lane) * 4];
      s[ti][tj] += b;
    }
  float mrow[4][4], srow[4][4];
#pragma unroll
  for (int ti = 0; ti < 4; ++ti)
#pragma unroll
    for (int r = 0; r < 4; ++r)
      mrow[ti][r] = fmaxf(fmaxf(s[ti][0][r], s[ti][1][r]), fmaxf(s[ti][2][r], s[ti][3][r]));
#pragma unroll
  for (int mask = 1; mask <= 8; mask <<= 1)
#pragma unroll
    for (int ti = 0; ti < 4; ++ti)
#pragma unroll
      for (int r = 0; r < 4; ++r)
        mrow[ti][r] = fmaxf(mrow[ti][r], __shfl_xor(mrow[ti][r], mask, 64));
#pragma unroll
  for (int ti = 0; ti < 4; ++ti)
#pragma unroll
    for (int tj = 0; tj < 4; ++tj)
#pragma unroll
      for (int r = 0; r < 4; ++r)
        s[ti][tj][r] = __expf(s[ti][tj][r] - mrow[ti][r]);
#pragma unroll
  for (int ti = 0; ti < 4; ++ti)
#pragma unroll
    for (int r = 0; r < 4; ++r)
      srow[ti][r] = s[ti][0][r] + s[ti][1][r] + s[ti][2][r] + s[ti][3][r];
#pragma unroll
  for (int mask = 1; mask <= 8; mask <<= 1)
#pragma unroll
    for (int ti = 0; ti < 4; ++ti)
#pragma unroll
      for (int r = 0; r < 4; ++r)
        srow[ti][r] += __shfl_xor(srow[ti][r], mask, 64);
  float inv[4][4];
#pragma unroll
  for (int ti = 0; ti < 4; ++ti)
#pragma unroll
    for (int r = 0; r < 4; ++r)
      inv[ti][r] = 1.0f / srow[ti][r];

#pragma unroll
  for (int ti = 0; ti < 4; ++ti)
#pragma unroll
    for (int tj = 0; tj < 4; ++tj)
#pragma unroll
      for (int r = 0; r < 4; ++r)
        Ps[(ti * 16 + quad * 4 + r) * 72 + tj * 16 + lm] = __float2bfloat16(s[ti][tj][r]);
  __builtin_amdgcn_s_waitcnt(0);

  f32x4 o[4][2];
#pragma unroll
  for (int mt = 0; mt < 4; ++mt)
#pragma unroll
    for (int nt = 0; nt < 2; ++nt)
#pragma unroll
      for (int r = 0; r < 4; ++r) o[mt][nt][r] = 0.f;
#pragma unroll
  for (int kq = 0; kq < 2; ++kq) {
    bf16x8 pa[4], vb[2];
#pragma unroll
    for (int mt = 0; mt < 4; ++mt)
      pa[mt] = *(const bf16x8*)&Ps[(mt * 16 + lm) * 72 + kq * 32 + quad * 8];
#pragma unroll
    for (int nt = 0; nt < 2; ++nt)
      vb[nt] = *(const bf16x8*)&Vt[(nt * 16 + lm) * 72 + kq * 32 + quad * 8];
#pragma unroll
    for (int mt = 0; mt < 4; ++mt)
#pragma unroll
      for (int nt = 0; nt < 2; ++nt)
        o[mt][nt] = __builtin_amdgcn_mfma_f32_16x16x32_bf16(pa[mt], vb[nt], o[mt][nt], 0, 0, 0);
  }
#pragma unroll
  for (int mt = 0; mt < 4; ++mt)
#pragma unroll
    for (int r = 0; r < 4; ++r) {
      int row = mt * 16 + quad * 4 + r;
      if (row < 49) {
#pragma unroll
        for (int nt = 0; nt < 2; ++nt)
          ob[(size_t)(wb * 49 + row) * 256 + h * 32 + nt * 16 + lm] =
              __float2bfloat16(o[mt][nt][r] * inv[mt][r]);
      }
    }
}

// ---------------------------------------------------------------------------
// (B,HW,256) fp32 -> (B,256,HW) fp32 via 32x32 LDS tiles.
__global__ void k_transpose(const float* __restrict__ y, float* __restrict__ out) {
  __shared__ float t[32][33];
  int bb = blockIdx.z;
  int hw0 = blockIdx.x * 32;
  int o0 = blockIdx.y * 32;
  int tx = threadIdx.x, ty = threadIdx.y;  // 32 x 8
#pragma unroll
  for (int r = 0; r < 4; ++r)
    t[ty + r * 8][tx] = y[(size_t)(bb * 3136 + hw0 + ty + r * 8) * 256 + o0 + tx];
  __syncthreads();
#pragma unroll
  for (int r = 0; r < 4; ++r)
    out[(size_t)(bb * 256 + o0 + ty + r * 8) * 3136 + hw0 + tx] = t[tx][ty + r * 8];
}

// ---------------------------------------------------------------------------
extern "C" void kernel_launch(void* const* d_in, const int* in_sizes, int n_in,
                              void* d_out, int out_size, void* d_ws, size_t ws_size,
                              hipStream_t stream) {
  const float* x_edge = (const float*)d_in[0];
  const float* x_body = (const float*)d_in[1];
  const float* ne_w   = (const float*)d_in[2];
  const float* ne_b   = (const float*)d_in[3];
  const float* conv_w = (const float*)d_in[4];
  const float* n1_w   = (const float*)d_in[5];
  const float* n1_b   = (const float*)d_in[6];
  const float* rpb    = (const float*)d_in[7];
  const float* q_w    = (const float*)d_in[8];
  const float* kv_w   = (const float*)d_in[9];
  const float* proj_w = (const float*)d_in[10];
  const float* proj_b = (const float*)d_in[11];
  const float* n2_w   = (const float*)d_in[12];
  const float* n2_b   = (const float*)d_in[13];
  const float* fc1_w  = (const float*)d_in[14];
  const float* fc1_b  = (const float*)d_in[15];
  const float* fc2_w  = (const float*)d_in[16];
  const float* fc2_b  = (const float*)d_in[17];
  float* out = (float*)d_out;
  (void)in_sizes; (void)n_in; (void)out_size; (void)ws_size;

  // ---- workspace layout (explicit, overlap-audited) ----
  const size_t SZ_Ae    = (size_t)M_ * 128 * 2;   //  12,845,056
  const size_t SZ_bf256 = (size_t)M_ * 256 * 2;   //  25,690,112
  const size_t SZ_bf512 = (size_t)M_ * 512 * 2;   //  51,380,224
  const size_t SZ_h1    = (size_t)M_ * 1024 * 2;  // 102,760,448

  char* ws = (char*)d_ws;
  __hip_bfloat16* Wb  = (__hip_bfloat16*)ws;                     // 1,638,400 B
  float* part  = (float*)(ws + 1638400);                         // 8 KB
  float* stats = (float*)(ws + 1638400 + 8192);                  // 256 B
  float* biasp = (float*)(ws + 1638400 + 8192 + 256);            // 131,072 B
  __hip_bfloat16* wqc = (__hip_bfloat16*)(ws + 1638400 + 8192 + 256 + 131072);  // 65,536 B
  char*  P     = ws + 1638400 + 8192 + 256 + 131072 + 65536;     // pool base
  __hip_bfloat16* w_kv   = Wb + 98304;
  __hip_bfloat16* w_proj = Wb + 229376;
  __hip_bfloat16* w_fc1  = Wb + 294912;
  __hip_bfloat16* w_fc2  = Wb + 557056;
  // Phase-1 pool (all dead by the fc1 GEMM):  xec eliminated (conv folded into q)
  __hip_bfloat16* Ae    = (__hip_bfloat16*)(P);
  __hip_bfloat16* xbn   = (__hip_bfloat16*)(P + SZ_Ae);
  __hip_bfloat16* qb    = (__hip_bfloat16*)(P + SZ_Ae + SZ_bf256);
  __hip_bfloat16* kvb   = (__hip_bfloat16*)(P + SZ_Ae + 2 * SZ_bf256);
  __hip_bfloat16* attnb = (__hip_bfloat16*)(P + SZ_Ae + 2 * SZ_bf256 + SZ_bf512);
  // h1 @ P+0 (everything above dead by fc1); xn/yb @ tail (past h1 end);
  // xf -> d_out (overwritten by final transpose)
  __hip_bfloat16* h1 = (__hip_bfloat16*)(P);
  char* tail         = P + ((SZ_h1 + 1024 * 1024) & ~(size_t)1023);
  __hip_bfloat16* xn = (__hip_bfloat16*)tail;
  float*          yb = (float*)tail;
  float*          xf = (float*)d_out;

  k_cast6<<<800, 256, 0, stream>>>(conv_w, q_w, kv_w, proj_w, fc1_w, fc2_w, Wb);
  k_wqc<<<256, 128, 0, stream>>>(q_w, conv_w, wqc);
  k_bias_pre<<<128, 64, 0, stream>>>(rpb, biasp);
  k_stats1<<<1024, 256, 0, stream>>>(x_edge, part);
  k_stats2<<<16, 64, 0, stream>>>(part, stats);
  k_prep_edge<<<1024, 256, 0, stream>>>(x_edge, ne_w, ne_b, stats, Ae);
  k_ln_rows<true><<<M_ / 4, 256, 0, stream>>>(x_body, n1_w, n1_b, xbn);
  // q = Ae @ W_qc^T (conv folded in, scale folded in)
  gemm_bt<0, 2><<<784, 256, 0, stream>>>(Ae, wqc, M_, 256, 128, qb, nullptr, nullptr, nullptr);
  // kv = xbn @ kv_w^T
  gemm_bt<0, 4><<<1568, 256, 0, stream>>>(xbn, w_kv, M_, 512, 256, kvb, nullptr, nullptr, nullptr);
  k_attn_mfma<<<8192, 64, 0, stream>>>(qb, kvb, biasp, attnb);
  // proj + bias + residual(x_body), windowed->natural rows, fp32 -> d_out (xf)
  gemm_bt<2, 2><<<784, 256, 0, stream>>>(attnb, w_proj, M_, 256, 256, nullptr, xf, proj_b, x_body);
  k_ln_rows<false><<<M_ / 4, 256, 0, stream>>>(xf, n2_w, n2_b, xn);
  // fc1 + bias + gelu(tanh)
  gemm_bt<3, 8><<<3136, 256, 0, stream>>>(xn, w_fc1, M_, 1024, 256, h1, nullptr, fc1_b, nullptr);
  // fc2 + bias + residual(xf)
  gemm_bt<4, 2><<<784, 256, 0, stream>>>(h1, w_fc2, M_, 256, 1024, nullptr, yb, fc2_b, xf);
  k_transpose<<<dim3(98, 8, 16), dim3(32, 8), 0, stream>>>(yb, out);
}

// Round 3
// 512.758 us; speedup vs baseline: 1.0599x; 1.0544x over previous
//
#include <hip/hip_runtime.h>
#include <hip/hip_bf16.h>
#include <math.h>

// Problem constants
#define B_    16
#define CE_   128
#define CB_   256
#define H_    56
#define W_    56
#define NH_   8
#define WS_   7
#define HD_   32
#define NWIN_ 49      // WS*WS
#define HW_   3136    // H*W
#define M_    50176   // B*H*W rows
#define HID_  1024

typedef short bf16x8 __attribute__((ext_vector_type(8)));
typedef float f32x4  __attribute__((ext_vector_type(4)));

__device__ __forceinline__ float waveRedSum(float v) {
#pragma unroll
  for (int off = 32; off; off >>= 1) v += __shfl_xor(v, off, 64);
  return v;
}

// Async global->LDS, 16B per lane.  LDS dest = wave-uniform base + lane*16.
__device__ __forceinline__ void load_lds16(const void* g, void* l) {
  __builtin_amdgcn_global_load_lds((__attribute__((address_space(1))) void*)g,
                                   (__attribute__((address_space(3))) void*)l,
                                   16, 0, 0);
}

// ---------------------------------------------------------------------------
// x_edge stats, stage 1: 1024 blocks (64 per batch), partial sums to ws.
__global__ void k_stats1(const float* __restrict__ xe, float* __restrict__ part) {
  int blk = blockIdx.x;
  int b = blk >> 6, s = blk & 63;
  const float4* p = (const float4*)(xe + (size_t)b * 401408 + s * 6272);
  float sm = 0.f, s2 = 0.f;
  for (int i = threadIdx.x; i < 1568; i += 256) {
    float4 v = p[i];
    sm += v.x + v.y + v.z + v.w;
    s2 += v.x * v.x + v.y * v.y + v.z * v.z + v.w * v.w;
  }
  sm = waveRedSum(sm); s2 = waveRedSum(s2);
  __shared__ float aux[8];
  int wave = threadIdx.x >> 6, lane = threadIdx.x & 63;
  if (lane == 0) { aux[wave] = sm; aux[4 + wave] = s2; }
  __syncthreads();
  if (threadIdx.x == 0) {
    part[blk * 2]     = aux[0] + aux[1] + aux[2] + aux[3];
    part[blk * 2 + 1] = aux[4] + aux[5] + aux[6] + aux[7];
  }
}

// stage 2: 16 blocks x 64 threads -> mean/rstd per batch.
__global__ void k_stats2(const float* __restrict__ part, float* __restrict__ stats) {
  int b = blockIdx.x, lane = threadIdx.x;
  float sm = part[(b * 64 + lane) * 2];
  float s2 = part[(b * 64 + lane) * 2 + 1];
  sm = waveRedSum(sm); s2 = waveRedSum(s2);
  if (lane == 0) {
    float mean = sm / 401408.0f;
    float var  = s2 / 401408.0f - mean * mean;
    stats[b * 2] = mean;
    stats[b * 2 + 1] = rsqrtf(var + 1e-5f);
  }
}

// ---------------------------------------------------------------------------
// Cast weight matrices fp32 -> bf16 into one contiguous buffer.
__global__ void k_cast6(const float* __restrict__ s0, const float* __restrict__ s1,
                        const float* __restrict__ s2, const float* __restrict__ s3,
                        const float* __restrict__ s4, const float* __restrict__ s5,
                        __hip_bfloat16* __restrict__ d) {
  size_t i4 = ((size_t)blockIdx.x * 256 + threadIdx.x) * 4;
  if (i4 >= 819200) return;
  const float* src; size_t off;
  if      (i4 < 32768)  { src = s0; off = 0; }
  else if (i4 < 98304)  { src = s1; off = 32768; }
  else if (i4 < 229376) { src = s2; off = 98304; }
  else if (i4 < 294912) { src = s3; off = 229376; }
  else if (i4 < 557056) { src = s4; off = 294912; }
  else                  { src = s5; off = 557056; }
  float4 v = *(const float4*)(src + (i4 - off));
  union { __hip_bfloat16 h[4]; uint2 u; } pk;
  pk.h[0] = __float2bfloat16(v.x);
  pk.h[1] = __float2bfloat16(v.y);
  pk.h[2] = __float2bfloat16(v.z);
  pk.h[3] = __float2bfloat16(v.w);
  *(uint2*)(d + i4) = pk.u;
}

// ---------------------------------------------------------------------------
// W_qc = qscale * q_w(256x256) @ conv_w(256x128) -> bf16 (256x128 row-major).
__global__ void k_wqc(const float* __restrict__ qw, const float* __restrict__ cw,
                      __hip_bfloat16* __restrict__ wqc) {
  int o2 = blockIdx.x, c = threadIdx.x;
  float acc = 0.f;
#pragma unroll 4
  for (int o = 0; o < 256; ++o)
    acc += qw[o2 * 256 + o] * cw[o * 128 + c];
  wqc[o2 * 128 + c] = __float2bfloat16(acc * 0.17677669529663687f);
}

// ---------------------------------------------------------------------------
// Precompute rel-pos bias in MFMA C-fragment order + padding mask.
__global__ void k_bias_pre(const float* __restrict__ rpb, float* __restrict__ bp) {
  int blk = blockIdx.x;         // h*16 + ti*4 + tj
  int h = blk >> 4, tile = blk & 15;
  int ti = tile >> 2, tj = tile & 3;
  int lane = threadIdx.x;
  int quad = lane >> 4, lm = lane & 15;
  float4 v;
  float* vp = (float*)&v;
#pragma unroll
  for (int r = 0; r < 4; ++r) {
    int i = ti * 16 + quad * 4 + r;
    int j = tj * 16 + lm;
    float b = -1e30f;
    if (i < 49 && j < 49) {
      int rel = (i / 7 - j / 7 + 6) * 13 + (i % 7 - j % 7 + 6);
      b = rpb[rel * 8 + h];
    }
    vp[r] = b;
  }
  *(float4*)&bp[(size_t)(blk * 64 + lane) * 4] = v;
}

// ---------------------------------------------------------------------------
// Normalize x_edge (per-element affine), emit bf16 A matrix in WINDOWED row
// order: row m = wb*49 + p, cols = 128 channels.  1024 blocks (one/window).
__global__ void k_prep_edge(const float* __restrict__ xe,
                            const float* __restrict__ we,
                            const float* __restrict__ be,
                            const float* __restrict__ stats,
                            __hip_bfloat16* __restrict__ Ae) {
  int wb = blockIdx.x;
  int b = wb >> 6, rem = wb & 63;
  int h0 = (rem >> 3) * 7, w0 = (rem & 7) * 7;
  float mean = stats[b * 2], rstd = stats[b * 2 + 1];
  __shared__ __hip_bfloat16 t[49 * 130];
  for (int idx = threadIdx.x; idx < 128 * 49; idx += 256) {
    int c = idx / 49, p = idx % 49;
    int h = h0 + p / 7, w = w0 + p % 7;
    int off = (c * 56 + h) * 56 + w;
    float v = xe[(size_t)b * 401408 + off];
    t[p * 130 + c] = __float2bfloat16((v - mean) * rstd * we[off] + be[off]);
  }
  __syncthreads();
  __hip_bfloat16* dst = Ae + (size_t)wb * 49 * 128;
  for (int idx = threadIdx.x; idx < 49 * 128; idx += 256) {
    int p = idx >> 7, c = idx & 127;
    dst[idx] = t[p * 130 + c];
  }
}

// ---------------------------------------------------------------------------
// Row LayerNorm over 256 channels; one wave per row, 4 rows/block.
template <bool PERM>
__global__ void k_ln_rows(const float* __restrict__ x,
                          const float* __restrict__ w,
                          const float* __restrict__ bia,
                          __hip_bfloat16* __restrict__ out) {
  int row = blockIdx.x * 4 + (threadIdx.x >> 6);
  int lane = threadIdx.x & 63;
  float4 xv = *(const float4*)(x + (size_t)row * 256 + lane * 4);
  float s  = xv.x + xv.y + xv.z + xv.w;
  float s2 = xv.x * xv.x + xv.y * xv.y + xv.z * xv.z + xv.w * xv.w;
  s = waveRedSum(s); s2 = waveRedSum(s2);
  float mean = s * (1.0f / 256.0f);
  float var  = s2 * (1.0f / 256.0f) - mean * mean;
  float rstd = rsqrtf(var + 1e-5f);
  int orow = row;
  if (PERM) {
    int b = row / 3136, hw = row % 3136;
    int h = hw / 56, ww = hw % 56;
    orow = (b * 64 + (h / 7) * 8 + (ww / 7)) * 49 + (h % 7) * 7 + (ww % 7);
  }
  float4 wv = *(const float4*)(w + lane * 4);
  float4 bv = *(const float4*)(bia + lane * 4);
  union { __hip_bfloat16 h[4]; uint2 u; } pk;
  pk.h[0] = __float2bfloat16((xv.x - mean) * rstd * wv.x + bv.x);
  pk.h[1] = __float2bfloat16((xv.y - mean) * rstd * wv.y + bv.y);
  pk.h[2] = __float2bfloat16((xv.z - mean) * rstd * wv.z + bv.z);
  pk.h[3] = __float2bfloat16((xv.w - mean) * rstd * wv.w + bv.w);
  *(uint2*)(out + (size_t)orow * 256 + lane * 4) = pk.u;
}

// ---------------------------------------------------------------------------
// MFMA GEMM:  C(MxN) = A(MxK,bf16) * W(NxK,bf16)^T   with epilogues.
// 128x128 tile, BK=32, 256 threads, 2-phase double-buffered K-loop.
// Epilogue: LDS-repacked — acc fragments staged to a padded 32x132 f32 LDS
// tile (4 passes), read back as float4 rows, stored as 16B coalesced stores.
// Bias is one float4/thread; resid is a coalesced float4 in the read phase.
// EPI: 0 store bf16 | 2 proj(+bias+resid, permute rows, f32)
//      3 bias+gelu(sigmoid-form) bf16 | 4 bias+resid f32
template <int EPI, int NX>
__launch_bounds__(256)
__global__ void gemm_bt(const __hip_bfloat16* __restrict__ A,
                        const __hip_bfloat16* __restrict__ Bw,
                        int M, int N, int K,
                        __hip_bfloat16* __restrict__ outb,
                        float* __restrict__ outf,
                        const float* __restrict__ bias,
                        const float* __restrict__ resid) {
  __shared__ __align__(16) char smem[32768];
  __hip_bfloat16* As0 = (__hip_bfloat16*)smem;            // 2 x 4096 elems
  __hip_bfloat16* Bs0 = (__hip_bfloat16*)(smem + 16384);  // 2 x 4096 elems
  const int tid  = threadIdx.x;
  const int lane = tid & 63;
  const int wave = tid >> 6;
  const int quad = lane >> 4;
  const int lm   = lane & 15;
  const int wm   = (wave & 1) << 6;
  const int wn   = (wave >> 1) << 6;
  // XCD-aware swizzle (392 bands = 8 XCDs x 49)
  const int lin  = blockIdx.x;
  const int slot = lin >> 3;
  const int band = (lin & 7) * 49 + slot / NX;
  const int n0   = (slot % NX) * 128;
  const int m0   = band * 128;

  const int rh = (wave & 1) * 64;   // row-half base
  const int qw = wave >> 1;         // base k-quad
  const __hip_bfloat16* Arow = A  + (size_t)(m0 + rh + lane) * K;
  const __hip_bfloat16* Brow = Bw + (size_t)(n0 + rh + lane) * K;

  f32x4 acc[4][4];
#pragma unroll
  for (int i = 0; i < 4; ++i)
#pragma unroll
    for (int j = 0; j < 4; ++j)
#pragma unroll
      for (int r = 0; r < 4; ++r) acc[i][j][r] = 0.f;

  // stage one BK=32 tile (A+B) into buffer `buf`
  auto STAGE = [&](int buf, int k0) {
#pragma unroll
    for (int p = 0; p < 2; ++p) {
      int q = qw + 2 * p;
      load_lds16(Arow + k0 + q * 8, As0 + buf * 4096 + (q * 128 + rh) * 8);
      load_lds16(Brow + k0 + q * 8, Bs0 + buf * 4096 + (q * 128 + rh) * 8);
    }
  };

  const int nt = K >> 5;
  // prologue: fill buffer 0, drain, barrier
  STAGE(0, 0);
  asm volatile("s_waitcnt vmcnt(0)" ::: "memory");
  __builtin_amdgcn_s_barrier();
  __builtin_amdgcn_sched_barrier(0);

  int cur = 0;
  for (int t = 0; t < nt; ++t) {
    // issue next tile's loads first — they fly under this tile's MFMAs
    if (t + 1 < nt) STAGE(cur ^ 1, (t + 1) << 5);
    bf16x8 af[4], bfr[4];
#pragma unroll
    for (int i = 0; i < 4; ++i)
      af[i] = *(const bf16x8*)(As0 + cur * 4096 + (quad * 128 + wm + i * 16 + lm) * 8);
#pragma unroll
    for (int j = 0; j < 4; ++j)
      bfr[j] = *(const bf16x8*)(Bs0 + cur * 4096 + (quad * 128 + wn + j * 16 + lm) * 8);
#pragma unroll
    for (int i = 0; i < 4; ++i)
#pragma unroll
      for (int j = 0; j < 4; ++j)
        acc[i][j] = __builtin_amdgcn_mfma_f32_16x16x32_bf16(af[i], bfr[j], acc[i][j], 0, 0, 0);
    if (t + 1 < nt) {
      asm volatile("s_waitcnt vmcnt(0)" ::: "memory");
      __builtin_amdgcn_s_barrier();
      __builtin_amdgcn_sched_barrier(0);
    }
    cur ^= 1;
  }

  // ---- epilogue: LDS-repacked coalesced stores ----
  float* R = (float*)smem;            // 32 x 132 f32 (16,896 B of the 32 KB)
  const int g    = tid >> 5;          // 0..7  row group
  const int lx   = tid & 31;          // 0..31 col lane (4 cols each)
  const int half = wave & 1;
  const int gncol = n0 + lx * 4;
  float4 b4;
  if constexpr (EPI != 0) b4 = *(const float4*)&bias[gncol];

#pragma unroll
  for (int i = 0; i < 4; ++i) {
    __syncthreads();                  // R free (main loop done / prev pass read)
#pragma unroll
    for (int r = 0; r < 4; ++r) {
      const int rl = half * 16 + quad * 4 + r;
#pragma unroll
      for (int j = 0; j < 4; ++j)
        R[rl * 132 + wn + j * 16 + lm] = acc[i][j][r];
    }
    __syncthreads();
#pragma unroll
    for (int p = 0; p < 4; ++p) {
      const int rl = p * 8 + g;
      f32x4 v4 = *(const f32x4*)&R[rl * 132 + lx * 4];
      const int gm = m0 + (rl >> 4) * 64 + i * 16 + (rl & 15);
      if constexpr (EPI == 0) {
        union { __hip_bfloat16 h[4]; uint2 u; } pk;
#pragma unroll
        for (int q2 = 0; q2 < 4; ++q2) pk.h[q2] = __float2bfloat16(v4[q2]);
        *(uint2*)&outb[(size_t)gm * N + gncol] = pk.u;
      } else if constexpr (EPI == 3) {
        // gelu(tanh-approx) in sigmoid form: x * sigmoid(1.5957691*(x+0.044715 x^3))
        // exp folded to exp2:  t = x*(GA + GB*x^2),  out = x * rcp(1 + 2^t)
        union { __hip_bfloat16 h[4]; uint2 u; } pk;
        const float* bp4 = (const float*)&b4;
#pragma unroll
        for (int q2 = 0; q2 < 4; ++q2) {
          float x = v4[q2] + bp4[q2];
          float t = x * fmaf(x * x, -0.10294324f, -2.30220837f);
          float e = __builtin_amdgcn_exp2f(t);
          pk.h[q2] = __float2bfloat16(x * __builtin_amdgcn_rcpf(1.0f + e));
        }
        *(uint2*)&outb[(size_t)gm * N + gncol] = pk.u;
      } else {
        size_t rowbase;
        if constexpr (EPI == 2) {
          int wb = gm / 49, nn = gm % 49;
          int b = wb >> 6, rem = wb & 63;
          int h = (rem >> 3) * 7 + nn / 7, w = (rem & 7) * 7 + nn % 7;
          rowbase = (size_t)(b * 3136 + h * 56 + w) * 256;
        } else {
          rowbase = (size_t)gm * N;
        }
        float4 r4 = *(const float4*)&resid[rowbase + gncol];
        float4 o4;
        o4.x = v4[0] + b4.x + r4.x;
        o4.y = v4[1] + b4.y + r4.y;
        o4.z = v4[2] + b4.z + r4.z;
        o4.w = v4[3] + b4.w + r4.w;
        *(float4*)&outf[rowbase + gncol] = o4;
      }
    }
  }
}

// ---------------------------------------------------------------------------
// MFMA windowed attention: one WAVE per (window, head).  8192 blocks x 64 thr.
__launch_bounds__(64)
__global__ void k_attn_mfma(const __hip_bfloat16* __restrict__ qb,
                            const __hip_bfloat16* __restrict__ kvb,
                            const float* __restrict__ bp,
                            __hip_bfloat16* __restrict__ ob) {
  int wb = blockIdx.x >> 3;
  int h  = blockIdx.x & 7;
  __shared__ __align__(16) __hip_bfloat16 lds[7424];
  __hip_bfloat16* Qs = lds;
  __hip_bfloat16* Ks = lds + 2560;
  __hip_bfloat16* Vt = lds + 5120;
  __hip_bfloat16* Ps = lds;
  const int lane = threadIdx.x;
  const int quad = lane >> 4, lm = lane & 15;

  const __hip_bfloat16 zb = __float2bfloat16(0.f);
  for (int i = lane; i < 600; i += 64) { Qs[1960 + i] = zb; Ks[1960 + i] = zb; }
  {
    uint4 z; z.x = z.y = z.z = z.w = 0u;
    for (int i = lane; i < 288; i += 64) ((uint4*)Vt)[i] = z;
  }
  {
    int t = lane >> 2, p = lane & 3;
#pragma unroll
    for (int pass = 0; pass < 4; ++pass, t += 16) {
      if (t < 49) {
        size_t rq = (size_t)(wb * 49 + t);
        uint4 qv = *(const uint4*)(qb + rq * 256 + h * 32 + p * 8);
        *(uint4*)&Qs[t * 40 + p * 8] = qv;
        uint4 kv = *(const uint4*)(kvb + rq * 512 + h * 32 + p * 8);
        *(uint4*)&Ks[t * 40 + p * 8] = kv;
        union { uint4 u; __hip_bfloat16 e[8]; } vv;
        vv.u = *(const uint4*)(kvb + rq * 512 + 256 + h * 32 + p * 8);
#pragma unroll
        for (int i = 0; i < 8; ++i) Vt[(p * 8 + i) * 72 + t] = vv.e[i];
      }
    }
  }
  __builtin_amdgcn_s_waitcnt(0);

  bf16x8 qf[4], kf[4];
#pragma unroll
  for (int i = 0; i < 4; ++i) qf[i] = *(const bf16x8*)&Qs[(i * 16 + lm) * 40 + quad * 8];
#pragma unroll
  for (int j = 0; j < 4; ++j) kf[j] = *(const bf16x8*)&Ks[(j * 16 + lm) * 40 + quad * 8];
  f32x4 s[4][4];
#pragma unroll
  for (int i = 0; i < 4; ++i)
#pragma unroll
    for (int j = 0; j < 4; ++j) {
      f32x4 z4; z4[0] = z4[1] = z4[2] = z4[3] = 0.f;
      s[i][j] = __builtin_amdgcn_mfma_f32_16x16x32_bf16(qf[i], kf[j], z4, 0, 0, 0);
    }
#pragma unroll
  for (int ti = 0; ti < 4; ++ti)
#pragma unroll
    for (int tj = 0; tj < 4; ++tj) {
      f32x4 b = *(const f32x4*)&bp[(size_t)(((h * 4 + ti) * 4 + tj) * 64 + lane) * 4];
      s[ti][tj] += b;
    }
  float mrow[4][4], srow[4][4];
#pragma unroll
  for (int ti = 0; ti < 4; ++ti)
#pragma unroll
    for (int r = 0; r < 4; ++r)
      mrow[ti][r] = fmaxf(fmaxf(s[ti][0][r], s[ti][1][r]), fmaxf(s[ti][2][r], s[ti][3][r]));
#pragma unroll
  for (int mask = 1; mask <= 8; mask <<= 1)
#pragma unroll
    for (int ti = 0; ti < 4; ++ti)
#pragma unroll
      for (int r = 0; r < 4; ++r)
        mrow[ti][r] = fmaxf(mrow[ti][r], __shfl_xor(mrow[ti][r], mask, 64));
#pragma unroll
  for (int ti = 0; ti < 4; ++ti)
#pragma unroll
    for (int tj = 0; tj < 4; ++tj)
#pragma unroll
      for (int r = 0; r < 4; ++r)
        s[ti][tj][r] = __expf(s[ti][tj][r] - mrow[ti][r]);
#pragma unroll
  for (int ti = 0; ti < 4; ++ti)
#pragma unroll
    for (int r = 0; r < 4; ++r)
      srow[ti][r] = s[ti][0][r] + s[ti][1][r] + s[ti][2][r] + s[ti][3][r];
#pragma unroll
  for (int mask = 1; mask <= 8; mask <<= 1)
#pragma unroll
    for (int ti = 0; ti < 4; ++ti)
#pragma unroll
      for (int r = 0; r < 4; ++r)
        srow[ti][r] += __shfl_xor(srow[ti][r], mask, 64);
  float inv[4][4];
#pragma unroll
  for (int ti = 0; ti < 4; ++ti)
#pragma unroll
    for (int r = 0; r < 4; ++r)
      inv[ti][r] = 1.0f / srow[ti][r];

#pragma unroll
  for (int ti = 0; ti < 4; ++ti)
#pragma unroll
    for (int tj = 0; tj < 4; ++tj)
#pragma unroll
      for (int r = 0; r < 4; ++r)
        Ps[(ti * 16 + quad * 4 + r) * 72 + tj * 16 + lm] = __float2bfloat16(s[ti][tj][r]);
  __builtin_amdgcn_s_waitcnt(0);

  f32x4 o[4][2];
#pragma unroll
  for (int mt = 0; mt < 4; ++mt)
#pragma unroll
    for (int nt = 0; nt < 2; ++nt)
#pragma unroll
      for (int r = 0; r < 4; ++r) o[mt][nt][r] = 0.f;
#pragma unroll
  for (int kq = 0; kq < 2; ++kq) {
    bf16x8 pa[4], vb[2];
#pragma unroll
    for (int mt = 0; mt < 4; ++mt)
      pa[mt] = *(const bf16x8*)&Ps[(mt * 16 + lm) * 72 + kq * 32 + quad * 8];
#pragma unroll
    for (int nt = 0; nt < 2; ++nt)
      vb[nt] = *(const bf16x8*)&Vt[(nt * 16 + lm) * 72 + kq * 32 + quad * 8];
#pragma unroll
    for (int mt = 0; mt < 4; ++mt)
#pragma unroll
      for (int nt = 0; nt < 2; ++nt)
        o[mt][nt] = __builtin_amdgcn_mfma_f32_16x16x32_bf16(pa[mt], vb[nt], o[mt][nt], 0, 0, 0);
  }
#pragma unroll
  for (int mt = 0; mt < 4; ++mt)
#pragma unroll
    for (int r = 0; r < 4; ++r) {
      int row = mt * 16 + quad * 4 + r;
      if (row < 49) {
#pragma unroll
        for (int nt = 0; nt < 2; ++nt)
          ob[(size_t)(wb * 49 + row) * 256 + h * 32 + nt * 16 + lm] =
              __float2bfloat16(o[mt][nt][r] * inv[mt][r]);
      }
    }
}

// ---------------------------------------------------------------------------
// (B,HW,256) fp32 -> (B,256,HW) fp32 via 32x32 LDS tiles.
__global__ void k_transpose(const float* __restrict__ y, float* __restrict__ out) {
  __shared__ float t[32][33];
  int bb = blockIdx.z;
  int hw0 = blockIdx.x * 32;
  int o0 = blockIdx.y * 32;
  int tx = threadIdx.x, ty = threadIdx.y;  // 32 x 8
#pragma unroll
  for (int r = 0; r < 4; ++r)
    t[ty + r * 8][tx] = y[(size_t)(bb * 3136 + hw0 + ty + r * 8) * 256 + o0 + tx];
  __syncthreads();
#pragma unroll
  for (int r = 0; r < 4; ++r)
    out[(size_t)(bb * 256 + o0 + ty + r * 8) * 3136 + hw0 + tx] = t[tx][ty + r * 8];
}

// ---------------------------------------------------------------------------
extern "C" void kernel_launch(void* const* d_in, const int* in_sizes, int n_in,
                              void* d_out, int out_size, void* d_ws, size_t ws_size,
                              hipStream_t stream) {
  const float* x_edge = (const float*)d_in[0];
  const float* x_body = (const float*)d_in[1];
  const float* ne_w   = (const float*)d_in[2];
  const float* ne_b   = (const float*)d_in[3];
  const float* conv_w = (const float*)d_in[4];
  const float* n1_w   = (const float*)d_in[5];
  const float* n1_b   = (const float*)d_in[6];
  const float* rpb    = (const float*)d_in[7];
  const float* q_w    = (const float*)d_in[8];
  const float* kv_w   = (const float*)d_in[9];
  const float* proj_w = (const float*)d_in[10];
  const float* proj_b = (const float*)d_in[11];
  const float* n2_w   = (const float*)d_in[12];
  const float* n2_b   = (const float*)d_in[13];
  const float* fc1_w  = (const float*)d_in[14];
  const float* fc1_b  = (const float*)d_in[15];
  const float* fc2_w  = (const float*)d_in[16];
  const float* fc2_b  = (const float*)d_in[17];
  float* out = (float*)d_out;
  (void)in_sizes; (void)n_in; (void)out_size; (void)ws_size;

  // ---- workspace layout (explicit, overlap-audited) ----
  const size_t SZ_Ae    = (size_t)M_ * 128 * 2;   //  12,845,056
  const size_t SZ_bf256 = (size_t)M_ * 256 * 2;   //  25,690,112
  const size_t SZ_bf512 = (size_t)M_ * 512 * 2;   //  51,380,224
  const size_t SZ_h1    = (size_t)M_ * 1024 * 2;  // 102,760,448

  char* ws = (char*)d_ws;
  __hip_bfloat16* Wb  = (__hip_bfloat16*)ws;                     // 1,638,400 B
  float* part  = (float*)(ws + 1638400);                         // 8 KB
  float* stats = (float*)(ws + 1638400 + 8192);                  // 256 B
  float* biasp = (float*)(ws + 1638400 + 8192 + 256);            // 131,072 B
  __hip_bfloat16* wqc = (__hip_bfloat16*)(ws + 1638400 + 8192 + 256 + 131072);  // 65,536 B
  char*  P     = ws + 1638400 + 8192 + 256 + 131072 + 65536;     // pool base
  __hip_bfloat16* w_kv   = Wb + 98304;
  __hip_bfloat16* w_proj = Wb + 229376;
  __hip_bfloat16* w_fc1  = Wb + 294912;
  __hip_bfloat16* w_fc2  = Wb + 557056;
  // Phase-1 pool (all dead by the fc1 GEMM):  xec eliminated (conv folded into q)
  __hip_bfloat16* Ae    = (__hip_bfloat16*)(P);
  __hip_bfloat16* xbn   = (__hip_bfloat16*)(P + SZ_Ae);
  __hip_bfloat16* qb    = (__hip_bfloat16*)(P + SZ_Ae + SZ_bf256);
  __hip_bfloat16* kvb   = (__hip_bfloat16*)(P + SZ_Ae + 2 * SZ_bf256);
  __hip_bfloat16* attnb = (__hip_bfloat16*)(P + SZ_Ae + 2 * SZ_bf256 + SZ_bf512);
  // h1 @ P+0 (everything above dead by fc1); xn/yb @ tail (past h1 end);
  // xf -> d_out (overwritten by final transpose)
  __hip_bfloat16* h1 = (__hip_bfloat16*)(P);
  char* tail         = P + ((SZ_h1 + 1024 * 1024) & ~(size_t)1023);
  __hip_bfloat16* xn = (__hip_bfloat16*)tail;
  float*          yb = (float*)tail;
  float*          xf = (float*)d_out;

  k_cast6<<<800, 256, 0, stream>>>(conv_w, q_w, kv_w, proj_w, fc1_w, fc2_w, Wb);
  k_wqc<<<256, 128, 0, stream>>>(q_w, conv_w, wqc);
  k_bias_pre<<<128, 64, 0, stream>>>(rpb, biasp);
  k_stats1<<<1024, 256, 0, stream>>>(x_edge, part);
  k_stats2<<<16, 64, 0, stream>>>(part, stats);
  k_prep_edge<<<1024, 256, 0, stream>>>(x_edge, ne_w, ne_b, stats, Ae);
  k_ln_rows<true><<<M_ / 4, 256, 0, stream>>>(x_body, n1_w, n1_b, xbn);
  // q = Ae @ W_qc^T (conv folded in, scale folded in)
  gemm_bt<0, 2><<<784, 256, 0, stream>>>(Ae, wqc, M_, 256, 128, qb, nullptr, nullptr, nullptr);
  // kv = xbn @ kv_w^T
  gemm_bt<0, 4><<<1568, 256, 0, stream>>>(xbn, w_kv, M_, 512, 256, kvb, nullptr, nullptr, nullptr);
  k_attn_mfma<<<8192, 64, 0, stream>>>(qb, kvb, biasp, attnb);
  // proj + bias + residual(x_body), windowed->natural rows, fp32 -> d_out (xf)
  gemm_bt<2, 2><<<784, 256, 0, stream>>>(attnb, w_proj, M_, 256, 256, nullptr, xf, proj_b, x_body);
  k_ln_rows<false><<<M_ / 4, 256, 0, stream>>>(xf, n2_w, n2_b, xn);
  // fc1 + bias + gelu
  gemm_bt<3, 8><<<3136, 256, 0, stream>>>(xn, w_fc1, M_, 1024, 256, h1, nullptr, fc1_b, nullptr);
  // fc2 + bias + residual(xf)
  gemm_bt<4, 2><<<784, 256, 0, stream>>>(h1, w_fc2, M_, 256, 1024, nullptr, yb, fc2_b, xf);
  k_transpose<<<dim3(98, 8, 16), dim3(32, 8), 0, stream>>>(yb, out);
}

// Round 4
// 507.657 us; speedup vs baseline: 1.0705x; 1.0100x over previous
//
#include <hip/hip_runtime.h>
#include <hip/hip_bf16.h>
#include <math.h>

// Problem constants
#define B_    16
#define CE_   128
#define CB_   256
#define H_    56
#define W_    56
#define NH_   8
#define WS_   7
#define HD_   32
#define NWIN_ 49      // WS*WS
#define HW_   3136    // H*W
#define M_    50176   // B*H*W rows
#define HID_  1024

typedef short bf16x8 __attribute__((ext_vector_type(8)));
typedef float f32x4  __attribute__((ext_vector_type(4)));

__device__ __forceinline__ float waveRedSum(float v) {
#pragma unroll
  for (int off = 32; off; off >>= 1) v += __shfl_xor(v, off, 64);
  return v;
}

// Async global->LDS, 16B per lane.  LDS dest = wave-uniform base + lane*16.
__device__ __forceinline__ void load_lds16(const void* g, void* l) {
  __builtin_amdgcn_global_load_lds((__attribute__((address_space(1))) void*)g,
                                   (__attribute__((address_space(3))) void*)l,
                                   16, 0, 0);
}

// ---------------------------------------------------------------------------
// x_edge stats, stage 1: 1024 blocks (64 per batch), partial sums to ws.
__global__ void k_stats1(const float* __restrict__ xe, float* __restrict__ part) {
  int blk = blockIdx.x;
  int b = blk >> 6, s = blk & 63;
  const float4* p = (const float4*)(xe + (size_t)b * 401408 + s * 6272);
  float sm = 0.f, s2 = 0.f;
  for (int i = threadIdx.x; i < 1568; i += 256) {
    float4 v = p[i];
    sm += v.x + v.y + v.z + v.w;
    s2 += v.x * v.x + v.y * v.y + v.z * v.z + v.w * v.w;
  }
  sm = waveRedSum(sm); s2 = waveRedSum(s2);
  __shared__ float aux[8];
  int wave = threadIdx.x >> 6, lane = threadIdx.x & 63;
  if (lane == 0) { aux[wave] = sm; aux[4 + wave] = s2; }
  __syncthreads();
  if (threadIdx.x == 0) {
    part[blk * 2]     = aux[0] + aux[1] + aux[2] + aux[3];
    part[blk * 2 + 1] = aux[4] + aux[5] + aux[6] + aux[7];
  }
}

// stage 2: 16 blocks x 64 threads -> mean/rstd per batch.
__global__ void k_stats2(const float* __restrict__ part, float* __restrict__ stats) {
  int b = blockIdx.x, lane = threadIdx.x;
  float sm = part[(b * 64 + lane) * 2];
  float s2 = part[(b * 64 + lane) * 2 + 1];
  sm = waveRedSum(sm); s2 = waveRedSum(s2);
  if (lane == 0) {
    float mean = sm / 401408.0f;
    float var  = s2 / 401408.0f - mean * mean;
    stats[b * 2] = mean;
    stats[b * 2 + 1] = rsqrtf(var + 1e-5f);
  }
}

// ---------------------------------------------------------------------------
// Cast weight matrices fp32 -> bf16 into one contiguous buffer.
__global__ void k_cast6(const float* __restrict__ s0, const float* __restrict__ s1,
                        const float* __restrict__ s2, const float* __restrict__ s3,
                        const float* __restrict__ s4, const float* __restrict__ s5,
                        __hip_bfloat16* __restrict__ d) {
  size_t i4 = ((size_t)blockIdx.x * 256 + threadIdx.x) * 4;
  if (i4 >= 819200) return;
  const float* src; size_t off;
  if      (i4 < 32768)  { src = s0; off = 0; }
  else if (i4 < 98304)  { src = s1; off = 32768; }
  else if (i4 < 229376) { src = s2; off = 98304; }
  else if (i4 < 294912) { src = s3; off = 229376; }
  else if (i4 < 557056) { src = s4; off = 294912; }
  else                  { src = s5; off = 557056; }
  float4 v = *(const float4*)(src + (i4 - off));
  union { __hip_bfloat16 h[4]; uint2 u; } pk;
  pk.h[0] = __float2bfloat16(v.x);
  pk.h[1] = __float2bfloat16(v.y);
  pk.h[2] = __float2bfloat16(v.z);
  pk.h[3] = __float2bfloat16(v.w);
  *(uint2*)(d + i4) = pk.u;
}

// ---------------------------------------------------------------------------
// W_qc = qscale * q_w(256x256) @ conv_w(256x128) -> bf16 (256x128 row-major).
__global__ void k_wqc(const float* __restrict__ qw, const float* __restrict__ cw,
                      __hip_bfloat16* __restrict__ wqc) {
  int o2 = blockIdx.x, c = threadIdx.x;
  float acc = 0.f;
#pragma unroll 4
  for (int o = 0; o < 256; ++o)
    acc += qw[o2 * 256 + o] * cw[o * 128 + c];
  wqc[o2 * 128 + c] = __float2bfloat16(acc * 0.17677669529663687f);
}

// ---------------------------------------------------------------------------
// Precompute rel-pos bias in MFMA C-fragment order + padding mask.
__global__ void k_bias_pre(const float* __restrict__ rpb, float* __restrict__ bp) {
  int blk = blockIdx.x;         // h*16 + ti*4 + tj
  int h = blk >> 4, tile = blk & 15;
  int ti = tile >> 2, tj = tile & 3;
  int lane = threadIdx.x;
  int quad = lane >> 4, lm = lane & 15;
  float4 v;
  float* vp = (float*)&v;
#pragma unroll
  for (int r = 0; r < 4; ++r) {
    int i = ti * 16 + quad * 4 + r;
    int j = tj * 16 + lm;
    float b = -1e30f;
    if (i < 49 && j < 49) {
      int rel = (i / 7 - j / 7 + 6) * 13 + (i % 7 - j % 7 + 6);
      b = rpb[rel * 8 + h];
    }
    vp[r] = b;
  }
  *(float4*)&bp[(size_t)(blk * 64 + lane) * 4] = v;
}

// ---------------------------------------------------------------------------
// Normalize x_edge (per-element affine), emit bf16 A matrix in WINDOWED row
// order: row m = wb*49 + p, cols = 128 channels.  1024 blocks (one/window).
__global__ void k_prep_edge(const float* __restrict__ xe,
                            const float* __restrict__ we,
                            const float* __restrict__ be,
                            const float* __restrict__ stats,
                            __hip_bfloat16* __restrict__ Ae) {
  int wb = blockIdx.x;
  int b = wb >> 6, rem = wb & 63;
  int h0 = (rem >> 3) * 7, w0 = (rem & 7) * 7;
  float mean = stats[b * 2], rstd = stats[b * 2 + 1];
  __shared__ __hip_bfloat16 t[49 * 130];
  for (int idx = threadIdx.x; idx < 128 * 49; idx += 256) {
    int c = idx / 49, p = idx % 49;
    int h = h0 + p / 7, w = w0 + p % 7;
    int off = (c * 56 + h) * 56 + w;
    float v = xe[(size_t)b * 401408 + off];
    t[p * 130 + c] = __float2bfloat16((v - mean) * rstd * we[off] + be[off]);
  }
  __syncthreads();
  __hip_bfloat16* dst = Ae + (size_t)wb * 49 * 128;
  for (int idx = threadIdx.x; idx < 49 * 128; idx += 256) {
    int p = idx >> 7, c = idx & 127;
    dst[idx] = t[p * 130 + c];
  }
}

// ---------------------------------------------------------------------------
// Row LayerNorm over 256 channels; one wave per row, 4 rows/block.
template <bool PERM>
__global__ void k_ln_rows(const float* __restrict__ x,
                          const float* __restrict__ w,
                          const float* __restrict__ bia,
                          __hip_bfloat16* __restrict__ out) {
  int row = blockIdx.x * 4 + (threadIdx.x >> 6);
  int lane = threadIdx.x & 63;
  float4 xv = *(const float4*)(x + (size_t)row * 256 + lane * 4);
  float s  = xv.x + xv.y + xv.z + xv.w;
  float s2 = xv.x * xv.x + xv.y * xv.y + xv.z * xv.z + xv.w * xv.w;
  s = waveRedSum(s); s2 = waveRedSum(s2);
  float mean = s * (1.0f / 256.0f);
  float var  = s2 * (1.0f / 256.0f) - mean * mean;
  float rstd = rsqrtf(var + 1e-5f);
  int orow = row;
  if (PERM) {
    int b = row / 3136, hw = row % 3136;
    int h = hw / 56, ww = hw % 56;
    orow = (b * 64 + (h / 7) * 8 + (ww / 7)) * 49 + (h % 7) * 7 + (ww % 7);
  }
  float4 wv = *(const float4*)(w + lane * 4);
  float4 bv = *(const float4*)(bia + lane * 4);
  union { __hip_bfloat16 h[4]; uint2 u; } pk;
  pk.h[0] = __float2bfloat16((xv.x - mean) * rstd * wv.x + bv.x);
  pk.h[1] = __float2bfloat16((xv.y - mean) * rstd * wv.y + bv.y);
  pk.h[2] = __float2bfloat16((xv.z - mean) * rstd * wv.z + bv.z);
  pk.h[3] = __float2bfloat16((xv.w - mean) * rstd * wv.w + bv.w);
  *(uint2*)(out + (size_t)orow * 256 + lane * 4) = pk.u;
}

// ---------------------------------------------------------------------------
// MFMA GEMM:  C(MxN) = A(MxK,bf16) * W(NxK,bf16)^T   with epilogues.
// 128x128 tile, BK=32, 256 threads.
// K-loop: prefetch-distance-2 pipeline, 4 LDS buffers, counted vmcnt:
//   iteration t stages tile t+2, waits vmcnt(8) (tiles t+1,t+2 in flight,
//   tile t confirmed landed), one barrier per iteration.  Buffer written at
//   iter t was last read at iter t-2 — safe (waves <=1 barrier apart).
// Epilogue: LDS-repacked — acc fragments staged to a padded 32x132 f32 LDS
// tile (4 passes), read back as float4 rows, stored as 16B coalesced stores.
// EPI: 0 store bf16 | 2 proj(+bias+resid, permute rows, f32)
//      3 bias+gelu(sigmoid-form) bf16 | 4 bias+resid f32
template <int EPI, int NX>
__launch_bounds__(256)
__global__ void gemm_bt(const __hip_bfloat16* __restrict__ A,
                        const __hip_bfloat16* __restrict__ Bw,
                        int M, int N, int K,
                        __hip_bfloat16* __restrict__ outb,
                        float* __restrict__ outf,
                        const float* __restrict__ bias,
                        const float* __restrict__ resid) {
  __shared__ __align__(16) char smem[65536];
  __hip_bfloat16* As0 = (__hip_bfloat16*)smem;            // 4 x 4096 elems
  __hip_bfloat16* Bs0 = (__hip_bfloat16*)(smem + 32768);  // 4 x 4096 elems
  const int tid  = threadIdx.x;
  const int lane = tid & 63;
  const int wave = tid >> 6;
  const int quad = lane >> 4;
  const int lm   = lane & 15;
  const int wm   = (wave & 1) << 6;
  const int wn   = (wave >> 1) << 6;
  // XCD-aware swizzle (392 bands = 8 XCDs x 49)
  const int lin  = blockIdx.x;
  const int slot = lin >> 3;
  const int band = (lin & 7) * 49 + slot / NX;
  const int n0   = (slot % NX) * 128;
  const int m0   = band * 128;

  const int rh = (wave & 1) * 64;   // row-half base
  const int qw = wave >> 1;         // base k-quad
  const __hip_bfloat16* Arow = A  + (size_t)(m0 + rh + lane) * K;
  const __hip_bfloat16* Brow = Bw + (size_t)(n0 + rh + lane) * K;

  f32x4 acc[4][4];
#pragma unroll
  for (int i = 0; i < 4; ++i)
#pragma unroll
    for (int j = 0; j < 4; ++j)
#pragma unroll
      for (int r = 0; r < 4; ++r) acc[i][j][r] = 0.f;

  // stage one BK=32 tile (A+B) into buffer `buf` (4 loads/thread)
  auto STAGE = [&](int buf, int k0) {
#pragma unroll
    for (int p = 0; p < 2; ++p) {
      int q = qw + 2 * p;
      load_lds16(Arow + k0 + q * 8, As0 + buf * 4096 + (q * 128 + rh) * 8);
      load_lds16(Brow + k0 + q * 8, Bs0 + buf * 4096 + (q * 128 + rh) * 8);
    }
  };

  const int nt = K >> 5;            // >= 4 for all call sites
  STAGE(0, 0);
  STAGE(1, 32);

  for (int t = 0; t < nt; ++t) {
    if (t + 2 < nt) {
      STAGE((t + 2) & 3, (t + 2) << 5);
      asm volatile("s_waitcnt vmcnt(8)" ::: "memory");   // tile t landed
    } else if (t + 1 < nt) {
      asm volatile("s_waitcnt vmcnt(4)" ::: "memory");
    } else {
      asm volatile("s_waitcnt vmcnt(0)" ::: "memory");
    }
    __builtin_amdgcn_s_barrier();
    __builtin_amdgcn_sched_barrier(0);
    const int cb = t & 3;
    bf16x8 af[4], bfr[4];
#pragma unroll
    for (int i = 0; i < 4; ++i)
      af[i] = *(const bf16x8*)(As0 + cb * 4096 + (quad * 128 + wm + i * 16 + lm) * 8);
#pragma unroll
    for (int j = 0; j < 4; ++j)
      bfr[j] = *(const bf16x8*)(Bs0 + cb * 4096 + (quad * 128 + wn + j * 16 + lm) * 8);
#pragma unroll
    for (int i = 0; i < 4; ++i)
#pragma unroll
      for (int j = 0; j < 4; ++j)
        acc[i][j] = __builtin_amdgcn_mfma_f32_16x16x32_bf16(af[i], bfr[j], acc[i][j], 0, 0, 0);
  }

  // ---- epilogue: LDS-repacked coalesced stores ----
  float* R = (float*)smem;            // 32 x 132 f32 (16,896 B of the 64 KB)
  const int g    = tid >> 5;          // 0..7  row group
  const int lx   = tid & 31;          // 0..31 col lane (4 cols each)
  const int half = wave & 1;
  const int gncol = n0 + lx * 4;
  float4 b4;
  if constexpr (EPI != 0) b4 = *(const float4*)&bias[gncol];

#pragma unroll
  for (int i = 0; i < 4; ++i) {
    __syncthreads();                  // R free (main loop done / prev pass read)
#pragma unroll
    for (int r = 0; r < 4; ++r) {
      const int rl = half * 16 + quad * 4 + r;
#pragma unroll
      for (int j = 0; j < 4; ++j)
        R[rl * 132 + wn + j * 16 + lm] = acc[i][j][r];
    }
    __syncthreads();
#pragma unroll
    for (int p = 0; p < 4; ++p) {
      const int rl = p * 8 + g;
      f32x4 v4 = *(const f32x4*)&R[rl * 132 + lx * 4];
      const int gm = m0 + (rl >> 4) * 64 + i * 16 + (rl & 15);
      if constexpr (EPI == 0) {
        union { __hip_bfloat16 h[4]; uint2 u; } pk;
#pragma unroll
        for (int q2 = 0; q2 < 4; ++q2) pk.h[q2] = __float2bfloat16(v4[q2]);
        *(uint2*)&outb[(size_t)gm * N + gncol] = pk.u;
      } else if constexpr (EPI == 3) {
        // gelu(tanh-approx) in sigmoid form: x * sigmoid(1.5957691*(x+0.044715 x^3))
        // exp folded to exp2:  t = x*(GA + GB*x^2),  out = x * rcp(1 + 2^t)
        union { __hip_bfloat16 h[4]; uint2 u; } pk;
        const float* bp4 = (const float*)&b4;
#pragma unroll
        for (int q2 = 0; q2 < 4; ++q2) {
          float x = v4[q2] + bp4[q2];
          float t = x * fmaf(x * x, -0.10294324f, -2.30220837f);
          float e = __builtin_amdgcn_exp2f(t);
          pk.h[q2] = __float2bfloat16(x * __builtin_amdgcn_rcpf(1.0f + e));
        }
        *(uint2*)&outb[(size_t)gm * N + gncol] = pk.u;
      } else {
        size_t rowbase;
        if constexpr (EPI == 2) {
          int wb = gm / 49, nn = gm % 49;
          int b = wb >> 6, rem = wb & 63;
          int h = (rem >> 3) * 7 + nn / 7, w = (rem & 7) * 7 + nn % 7;
          rowbase = (size_t)(b * 3136 + h * 56 + w) * 256;
        } else {
          rowbase = (size_t)gm * N;
        }
        float4 r4 = *(const float4*)&resid[rowbase + gncol];
        float4 o4;
        o4.x = v4[0] + b4.x + r4.x;
        o4.y = v4[1] + b4.y + r4.y;
        o4.z = v4[2] + b4.z + r4.z;
        o4.w = v4[3] + b4.w + r4.w;
        *(float4*)&outf[rowbase + gncol] = o4;
      }
    }
  }
}

// ---------------------------------------------------------------------------
// MFMA windowed attention: one WAVE per (window, head).  8192 blocks x 64 thr.
__launch_bounds__(64)
__global__ void k_attn_mfma(const __hip_bfloat16* __restrict__ qb,
                            const __hip_bfloat16* __restrict__ kvb,
                            const float* __restrict__ bp,
                            __hip_bfloat16* __restrict__ ob) {
  int wb = blockIdx.x >> 3;
  int h  = blockIdx.x & 7;
  __shared__ __align__(16) __hip_bfloat16 lds[7424];
  __hip_bfloat16* Qs = lds;
  __hip_bfloat16* Ks = lds + 2560;
  __hip_bfloat16* Vt = lds + 5120;
  __hip_bfloat16* Ps = lds;
  const int lane = threadIdx.x;
  const int quad = lane >> 4, lm = lane & 15;

  const __hip_bfloat16 zb = __float2bfloat16(0.f);
  for (int i = lane; i < 600; i += 64) { Qs[1960 + i] = zb; Ks[1960 + i] = zb; }
  {
    uint4 z; z.x = z.y = z.z = z.w = 0u;
    for (int i = lane; i < 288; i += 64) ((uint4*)Vt)[i] = z;
  }
  {
    int t = lane >> 2, p = lane & 3;
#pragma unroll
    for (int pass = 0; pass < 4; ++pass, t += 16) {
      if (t < 49) {
        size_t rq = (size_t)(wb * 49 + t);
        uint4 qv = *(const uint4*)(qb + rq * 256 + h * 32 + p * 8);
        *(uint4*)&Qs[t * 40 + p * 8] = qv;
        uint4 kv = *(const uint4*)(kvb + rq * 512 + h * 32 + p * 8);
        *(uint4*)&Ks[t * 40 + p * 8] = kv;
        union { uint4 u; __hip_bfloat16 e[8]; } vv;
        vv.u = *(const uint4*)(kvb + rq * 512 + 256 + h * 32 + p * 8);
#pragma unroll
        for (int i = 0; i < 8; ++i) Vt[(p * 8 + i) * 72 + t] = vv.e[i];
      }
    }
  }
  __builtin_amdgcn_s_waitcnt(0);

  bf16x8 qf[4], kf[4];
#pragma unroll
  for (int i = 0; i < 4; ++i) qf[i] = *(const bf16x8*)&Qs[(i * 16 + lm) * 40 + quad * 8];
#pragma unroll
  for (int j = 0; j < 4; ++j) kf[j] = *(const bf16x8*)&Ks[(j * 16 + lm) * 40 + quad * 8];
  f32x4 s[4][4];
#pragma unroll
  for (int i = 0; i < 4; ++i)
#pragma unroll
    for (int j = 0; j < 4; ++j) {
      f32x4 z4; z4[0] = z4[1] = z4[2] = z4[3] = 0.f;
      s[i][j] = __builtin_amdgcn_mfma_f32_16x16x32_bf16(qf[i], kf[j], z4, 0, 0, 0);
    }
#pragma unroll
  for (int ti = 0; ti < 4; ++ti)
#pragma unroll
    for (int tj = 0; tj < 4; ++tj) {
      f32x4 b = *(const f32x4*)&bp[(size_t)(((h * 4 + ti) * 4 + tj) * 64 + lane) * 4];
      s[ti][tj] += b;
    }
  float mrow[4][4], srow[4][4];
#pragma unroll
  for (int ti = 0; ti < 4; ++ti)
#pragma unroll
    for (int r = 0; r < 4; ++r)
      mrow[ti][r] = fmaxf(fmaxf(s[ti][0][r], s[ti][1][r]), fmaxf(s[ti][2][r], s[ti][3][r]));
#pragma unroll
  for (int mask = 1; mask <= 8; mask <<= 1)
#pragma unroll
    for (int ti = 0; ti < 4; ++ti)
#pragma unroll
      for (int r = 0; r < 4; ++r)
        mrow[ti][r] = fmaxf(mrow[ti][r], __shfl_xor(mrow[ti][r], mask, 64));
#pragma unroll
  for (int ti = 0; ti < 4; ++ti)
#pragma unroll
    for (int tj = 0; tj < 4; ++tj)
#pragma unroll
      for (int r = 0; r < 4; ++r)
        s[ti][tj][r] = __expf(s[ti][tj][r] - mrow[ti][r]);
#pragma unroll
  for (int ti = 0; ti < 4; ++ti)
#pragma unroll
    for (int r = 0; r < 4; ++r)
      srow[ti][r] = s[ti][0][r] + s[ti][1][r] + s[ti][2][r] + s[ti][3][r];
#pragma unroll
  for (int mask = 1; mask <= 8; mask <<= 1)
#pragma unroll
    for (int ti = 0; ti < 4; ++ti)
#pragma unroll
      for (int r = 0; r < 4; ++r)
        srow[ti][r] += __shfl_xor(srow[ti][r], mask, 64);
  float inv[4][4];
#pragma unroll
  for (int ti = 0; ti < 4; ++ti)
#pragma unroll
    for (int r = 0; r < 4; ++r)
      inv[ti][r] = 1.0f / srow[ti][r];

#pragma unroll
  for (int ti = 0; ti < 4; ++ti)
#pragma unroll
    for (int tj = 0; tj < 4; ++tj)
#pragma unroll
      for (int r = 0; r < 4; ++r)
        Ps[(ti * 16 + quad * 4 + r) * 72 + tj * 16 + lm] = __float2bfloat16(s[ti][tj][r]);
  __builtin_amdgcn_s_waitcnt(0);

  f32x4 o[4][2];
#pragma unroll
  for (int mt = 0; mt < 4; ++mt)
#pragma unroll
    for (int nt = 0; nt < 2; ++nt)
#pragma unroll
      for (int r = 0; r < 4; ++r) o[mt][nt][r] = 0.f;
#pragma unroll
  for (int kq = 0; kq < 2; ++kq) {
    bf16x8 pa[4], vb[2];
#pragma unroll
    for (int mt = 0; mt < 4; ++mt)
      pa[mt] = *(const bf16x8*)&Ps[(mt * 16 + lm) * 72 + kq * 32 + quad * 8];
#pragma unroll
    for (int nt = 0; nt < 2; ++nt)
      vb[nt] = *(const bf16x8*)&Vt[(nt * 16 + lm) * 72 + kq * 32 + quad * 8];
#pragma unroll
    for (int mt = 0; mt < 4; ++mt)
#pragma unroll
      for (int nt = 0; nt < 2; ++nt)
        o[mt][nt] = __builtin_amdgcn_mfma_f32_16x16x32_bf16(pa[mt], vb[nt], o[mt][nt], 0, 0, 0);
  }
#pragma unroll
  for (int mt = 0; mt < 4; ++mt)
#pragma unroll
    for (int r = 0; r < 4; ++r) {
      int row = mt * 16 + quad * 4 + r;
      if (row < 49) {
#pragma unroll
        for (int nt = 0; nt < 2; ++nt)
          ob[(size_t)(wb * 49 + row) * 256 + h * 32 + nt * 16 + lm] =
              __float2bfloat16(o[mt][nt][r] * inv[mt][r]);
      }
    }
}

// ---------------------------------------------------------------------------
// (B,HW,256) fp32 -> (B,256,HW) fp32 via 32x32 LDS tiles.
__global__ void k_transpose(const float* __restrict__ y, float* __restrict__ out) {
  __shared__ float t[32][33];
  int bb = blockIdx.z;
  int hw0 = blockIdx.x * 32;
  int o0 = blockIdx.y * 32;
  int tx = threadIdx.x, ty = threadIdx.y;  // 32 x 8
#pragma unroll
  for (int r = 0; r < 4; ++r)
    t[ty + r * 8][tx] = y[(size_t)(bb * 3136 + hw0 + ty + r * 8) * 256 + o0 + tx];
  __syncthreads();
#pragma unroll
  for (int r = 0; r < 4; ++r)
    out[(size_t)(bb * 256 + o0 + ty + r * 8) * 3136 + hw0 + tx] = t[tx][ty + r * 8];
}

// ---------------------------------------------------------------------------
extern "C" void kernel_launch(void* const* d_in, const int* in_sizes, int n_in,
                              void* d_out, int out_size, void* d_ws, size_t ws_size,
                              hipStream_t stream) {
  const float* x_edge = (const float*)d_in[0];
  const float* x_body = (const float*)d_in[1];
  const float* ne_w   = (const float*)d_in[2];
  const float* ne_b   = (const float*)d_in[3];
  const float* conv_w = (const float*)d_in[4];
  const float* n1_w   = (const float*)d_in[5];
  const float* n1_b   = (const float*)d_in[6];
  const float* rpb    = (const float*)d_in[7];
  const float* q_w    = (const float*)d_in[8];
  const float* kv_w   = (const float*)d_in[9];
  const float* proj_w = (const float*)d_in[10];
  const float* proj_b = (const float*)d_in[11];
  const float* n2_w   = (const float*)d_in[12];
  const float* n2_b   = (const float*)d_in[13];
  const float* fc1_w  = (const float*)d_in[14];
  const float* fc1_b  = (const float*)d_in[15];
  const float* fc2_w  = (const float*)d_in[16];
  const float* fc2_b  = (const float*)d_in[17];
  float* out = (float*)d_out;
  (void)in_sizes; (void)n_in; (void)out_size; (void)ws_size;

  // ---- workspace layout (explicit, overlap-audited) ----
  const size_t SZ_Ae    = (size_t)M_ * 128 * 2;   //  12,845,056
  const size_t SZ_bf256 = (size_t)M_ * 256 * 2;   //  25,690,112
  const size_t SZ_bf512 = (size_t)M_ * 512 * 2;   //  51,380,224
  const size_t SZ_h1    = (size_t)M_ * 1024 * 2;  // 102,760,448

  char* ws = (char*)d_ws;
  __hip_bfloat16* Wb  = (__hip_bfloat16*)ws;                     // 1,638,400 B
  float* part  = (float*)(ws + 1638400);                         // 8 KB
  float* stats = (float*)(ws + 1638400 + 8192);                  // 256 B
  float* biasp = (float*)(ws + 1638400 + 8192 + 256);            // 131,072 B
  __hip_bfloat16* wqc = (__hip_bfloat16*)(ws + 1638400 + 8192 + 256 + 131072);  // 65,536 B
  char*  P     = ws + 1638400 + 8192 + 256 + 131072 + 65536;     // pool base
  __hip_bfloat16* w_kv   = Wb + 98304;
  __hip_bfloat16* w_proj = Wb + 229376;
  __hip_bfloat16* w_fc1  = Wb + 294912;
  __hip_bfloat16* w_fc2  = Wb + 557056;
  // Phase-1 pool (all dead by the fc1 GEMM):  xec eliminated (conv folded into q)
  __hip_bfloat16* Ae    = (__hip_bfloat16*)(P);
  __hip_bfloat16* xbn   = (__hip_bfloat16*)(P + SZ_Ae);
  __hip_bfloat16* qb    = (__hip_bfloat16*)(P + SZ_Ae + SZ_bf256);
  __hip_bfloat16* kvb   = (__hip_bfloat16*)(P + SZ_Ae + 2 * SZ_bf256);
  __hip_bfloat16* attnb = (__hip_bfloat16*)(P + SZ_Ae + 2 * SZ_bf256 + SZ_bf512);
  // h1 @ P+0 (everything above dead by fc1); xn/yb @ tail (past h1 end);
  // xf -> d_out (overwritten by final transpose)
  __hip_bfloat16* h1 = (__hip_bfloat16*)(P);
  char* tail         = P + ((SZ_h1 + 1024 * 1024) & ~(size_t)1023);
  __hip_bfloat16* xn = (__hip_bfloat16*)tail;
  float*          yb = (float*)tail;
  float*          xf = (float*)d_out;

  k_cast6<<<800, 256, 0, stream>>>(conv_w, q_w, kv_w, proj_w, fc1_w, fc2_w, Wb);
  k_wqc<<<256, 128, 0, stream>>>(q_w, conv_w, wqc);
  k_bias_pre<<<128, 64, 0, stream>>>(rpb, biasp);
  k_stats1<<<1024, 256, 0, stream>>>(x_edge, part);
  k_stats2<<<16, 64, 0, stream>>>(part, stats);
  k_prep_edge<<<1024, 256, 0, stream>>>(x_edge, ne_w, ne_b, stats, Ae);
  k_ln_rows<true><<<M_ / 4, 256, 0, stream>>>(x_body, n1_w, n1_b, xbn);
  // q = Ae @ W_qc^T (conv folded in, scale folded in)
  gemm_bt<0, 2><<<784, 256, 0, stream>>>(Ae, wqc, M_, 256, 128, qb, nullptr, nullptr, nullptr);
  // kv = xbn @ kv_w^T
  gemm_bt<0, 4><<<1568, 256, 0, stream>>>(xbn, w_kv, M_, 512, 256, kvb, nullptr, nullptr, nullptr);
  k_attn_mfma<<<8192, 64, 0, stream>>>(qb, kvb, biasp, attnb);
  // proj + bias + residual(x_body), windowed->natural rows, fp32 -> d_out (xf)
  gemm_bt<2, 2><<<784, 256, 0, stream>>>(attnb, w_proj, M_, 256, 256, nullptr, xf, proj_b, x_body);
  k_ln_rows<false><<<M_ / 4, 256, 0, stream>>>(xf, n2_w, n2_b, xn);
  // fc1 + bias + gelu
  gemm_bt<3, 8><<<3136, 256, 0, stream>>>(xn, w_fc1, M_, 1024, 256, h1, nullptr, fc1_b, nullptr);
  // fc2 + bias + residual(xf)
  gemm_bt<4, 2><<<784, 256, 0, stream>>>(h1, w_fc2, M_, 256, 1024, nullptr, yb, fc2_b, xf);
  k_transpose<<<dim3(98, 8, 16), dim3(32, 8), 0, stream>>>(yb, out);
}